// Round 10
// baseline (689.472 us; speedup 1.0000x reference)
//
#include <hip/hip_runtime.h>

typedef unsigned short u16;
typedef unsigned int u32;
typedef __attribute__((ext_vector_type(8))) short bf16x8;
typedef __attribute__((ext_vector_type(4))) float f32x4;
typedef __attribute__((ext_vector_type(16))) float f32x16;

#define TR 261888           // total anchor rows per batch image
#define LOGITS_OFF 0
#define PROBS_OFF  1047552  // 2*TR*2
#define DELTAS_OFF 2095104  // 2*(2*TR*2)

#define W3P_ELEMS (72 * 512 * 32)
#define W18P_ELEMS (32 * 512)
#define FLAG_OFF_BYTES ((W3P_ELEMS + W18P_ELEMS) * 2)   // 2,392,064
#define PART0_OFF 2392320                                // 256-aligned
#define NPIX 174592                                      // total pixels (2 batches)
#define PART_ELEMS (NPIX * 18)
#define PART_BYTES (PART_ELEMS * 4)

__device__ __forceinline__ float b2f(u16 u) {
    union { u32 i; float f; } v; v.i = ((u32)u) << 16; return v.f;
}
__device__ __forceinline__ u16 f2b(float f) {
    union { float f; u32 i; } v; v.f = f;
    u32 x = v.i;
    return (u16)((x + 0x7fffu + ((x >> 16) & 1u)) >> 16);
}
__device__ __forceinline__ float ldmix(const void* p, int i, bool isb16) {
    return isb16 ? b2f(((const u16*)p)[i]) : ((const float*)p)[i];
}

// Sh layout (fused fallback): 64 px x 512 ch, stride 512, XOR swizzle.
__device__ __forceinline__ int sh_idx(int px, int c) {
    return px * 512 + (c ^ ((px & 3) * 8));
}

// ---------------------------------------------------------------------------
// Detect input dtype.
// ---------------------------------------------------------------------------
__global__ void detect_kernel(const u16* __restrict__ f0, int* __restrict__ flag) {
    int lane = threadIdx.x;          // 64 threads
    u16 v = f0[lane * 2];            // even u16 index
    int e = (v >> 7) & 0xFF;
    bool plausible = (e >= 90) && (e <= 140);
    unsigned long long m = __ballot(plausible);
    if (lane == 0) *flag = (__popcll(m) >= 48) ? 1 : 0;   // 1 = bf16, 0 = f32
}

// ---------------------------------------------------------------------------
// Repack: w_shared [2304,512] -> W3p[72][512][32] bf16
//   w_cls[512,6] + w_delta[512,12] -> W18p[32][512] bf16 (rows 18..31 = 0)
// ---------------------------------------------------------------------------
__global__ void repack_kernel(const void* __restrict__ w3,
                              const void* __restrict__ wcls,
                              const void* __restrict__ wdelta,
                              u16* __restrict__ W3p, u16* __restrict__ W18p,
                              const int* __restrict__ flag) {
    const bool isb16 = (*flag != 0);
    int tid = blockIdx.x * 256 + threadIdx.x;
    if (tid < W3P_ELEMS) {
        int k = tid & 31;
        int n = (tid >> 5) & 511;
        int c = tid >> 14;
        int K = c * 32 + k;          // global k index 0..2303
        float v = ldmix(w3, K * 512 + n, isb16);
        W3p[tid] = f2b(v);
    } else if (tid < W3P_ELEMS + W18P_ELEMS) {
        int t = tid - W3P_ELEMS;
        int k = t & 511;
        int j = t >> 9;
        float v = 0.f;
        if (j < 6)       v = ldmix(wcls, k * 6 + j, isb16);
        else if (j < 18) v = ldmix(wdelta, k * 12 + (j - 6), isb16);
        W18p[t] = f2b(v);
    }
}

// ---------------------------------------------------------------------------
// N-split conv kernel, 32x32x16 MFMA (R5 structure, measured 525 us) with the
// R9-verified 4-bit halo swizzle (measured 5.2x fewer bank conflicts).
// One block = one 8x8 tile x one 256-channel half; 3 waves/SIMD.
// Halo swizzle: slot = cg ^ ((p&7) | ((row&1)<<3)) -> 32-lane A-read 2-way.
// ---------------------------------------------------------------------------
__global__ __launch_bounds__(256, 3) void rpn_conv(
    const void* __restrict__ f0, const void* __restrict__ f1,
    const void* __restrict__ f2, const void* __restrict__ f3,
    const void* __restrict__ f4,
    const void* __restrict__ bsh,
    const u16* __restrict__ W3p, const u16* __restrict__ W18p,
    float* __restrict__ Ppart, const int* __restrict__ flag)
{
    __shared__ u16 SMEM[25600];   // 51,200 B: halo 100px x 256ch bf16

    const bool isb16 = (*flag != 0);

    const int tid  = threadIdx.x;
    const int wv   = tid >> 6;
    const int lane = tid & 63;
    const int l32  = lane & 31;
    const int hi   = lane >> 5;          // 0/1: k-half selector for 32x32x16
    const int quad = lane >> 4;          // for GEMM2 (16x16)
    const int l16  = lane & 15;

    const int gid    = blockIdx.x;
    const int tileId = gid >> 1;
    const int nhalf  = gid & 1;

    const int lvl = (tileId >= 2048) + (tileId >= 2560) + (tileId >= 2688) + (tileId >= 2720);
    const int tileBase = (lvl == 0) ? 0 : (lvl == 1) ? 2048 : (lvl == 2) ? 2560
                        : (lvl == 3) ? 2688 : 2720;
    const int logS   = 8 - lvl;
    const int S      = 1 << logS;
    const int lvlPixOff = (lvl == 0) ? 0 : (lvl == 1) ? 65536 : (lvl == 2) ? 81920
                         : (lvl == 3) ? 86016 : 87040;
    const void* feat = (lvl == 0) ? f0 : (lvl == 1) ? f1 : (lvl == 2) ? f2
                      : (lvl == 3) ? f3 : f4;
    const int tile = tileId - tileBase;

    const int logT = logS - 3;
    const int b    = tile >> (2 * logT);
    const int t2   = tile & ((1 << (2 * logT)) - 1);
    const int th   = t2 >> logT;
    const int tw   = t2 & ((1 << logT) - 1);
    const int h0   = th << 3, w0 = tw << 3;

    // ---------------- stage 10x10x256 halo -> LDS (bf16, 4-bit swizzle) -----
    for (int g = tid; g < 3200; g += 256) {
        const int p  = g >> 5;
        const int cg = g & 31;
        const int hh = p / 10;
        const int ww = p - hh * 10;
        const int ih = h0 + hh - 1;
        const int iw = w0 + ww - 1;
        uint4 v; v.x = 0u; v.y = 0u; v.z = 0u; v.w = 0u;
        if (ih >= 0 && ih < S && iw >= 0 && iw < S) {
            const size_t gaddr = ((size_t)((b * S + ih) * S + iw)) * 256 + cg * 8;
            if (isb16) {
                v = *(const uint4*)((const u16*)feat + gaddr);
            } else {
                const float* fp = (const float*)feat + gaddr;
                float4 x = *(const float4*)fp;
                float4 y = *(const float4*)(fp + 4);
                v.x = (u32)f2b(x.x) | ((u32)f2b(x.y) << 16);
                v.y = (u32)f2b(x.z) | ((u32)f2b(x.w) << 16);
                v.z = (u32)f2b(y.x) | ((u32)f2b(y.y) << 16);
                v.w = (u32)f2b(y.z) | ((u32)f2b(y.w) << 16);
            }
        }
        const int sw = (p & 7) | ((hh & 1) << 3);
        *(uint4*)&SMEM[p * 256 + ((cg ^ sw) << 3)] = v;
    }
    __syncthreads();

    f32x16 acc[2][2];
#pragma unroll
    for (int mt = 0; mt < 2; ++mt)
#pragma unroll
        for (int nt = 0; nt < 2; ++nt)
#pragma unroll
            for (int r = 0; r < 16; ++r) acc[mt][nt][r] = 0.f;

    // lane's base halo pixel for Mt=0, center tap: px = l32 -> (row,col)
    const int pLane32 = ((l32 >> 3) + 1) * 10 + (l32 & 7) + 1;
    // W base: n = nhalf*256 + wv*64 + Nt*32 + l32, k-offset hi*8 within chunk
    const u16* __restrict__ Wp =
        W3p + (u32)(nhalf * 256 + wv * 64 + l32) * 32 + (u32)hi * 8;

    // depth-2 W queue: frag index = Nt*2 + ks -> Wp[kc*16384 + Nt*1024 + ks*16]
    bf16x8 wqE[4], wqO[4];
#pragma unroll
    for (int i = 0; i < 4; ++i) {
        wqE[i] = *(const bf16x8*)&Wp[0 * 16384 + (i >> 1) * 1024 + (i & 1) * 16];
        wqO[i] = *(const bf16x8*)&Wp[1 * 16384 + (i >> 1) * 1024 + (i & 1) * 16];
    }

    // one chunk: 4 ds_read A-frags (Mt x ks), 8 MFMA 32x32x16, refill queue
#define CHUNK(CC, WQ)                                                         \
    {                                                                         \
        const int kc = tap * 8 + (CC);                                        \
        bf16x8 af[2][2];                                                      \
        _Pragma("unroll")                                                     \
        for (int mt = 0; mt < 2; ++mt)                                        \
            _Pragma("unroll")                                                 \
            for (int ks = 0; ks < 2; ++ks)                                    \
                af[mt][ks] = *(const bf16x8*)                                 \
                    &SMEM[sbase[mt] +                                         \
                          ((((CC) * 4 + ks * 2 + hi) ^ sx[mt]) << 3)];        \
        __builtin_amdgcn_s_setprio(1);                                        \
        _Pragma("unroll")                                                     \
        for (int ks = 0; ks < 2; ++ks)                                        \
            _Pragma("unroll")                                                 \
            for (int nt = 0; nt < 2; ++nt)                                    \
                acc[mt_dummy][nt] = acc[mt_dummy][nt];                        \
        _Pragma("unroll")                                                     \
        for (int ks = 0; ks < 2; ++ks)                                        \
            _Pragma("unroll")                                                 \
            for (int nt = 0; nt < 2; ++nt) {                                  \
                acc[0][nt] = __builtin_amdgcn_mfma_f32_32x32x16_bf16(         \
                    af[0][ks], WQ[nt * 2 + ks], acc[0][nt], 0, 0, 0);         \
                acc[1][nt] = __builtin_amdgcn_mfma_f32_32x32x16_bf16(         \
                    af[1][ks], WQ[nt * 2 + ks], acc[1][nt], 0, 0, 0);         \
            }                                                                 \
        __builtin_amdgcn_s_setprio(0);                                        \
        const int kpre = (kc + 2 < 72) ? (kc + 2) : kc;                       \
        _Pragma("unroll")                                                     \
        for (int i = 0; i < 4; ++i)                                           \
            WQ[i] = *(const bf16x8*)                                          \
                &Wp[(size_t)kpre * 16384 + (i >> 1) * 1024 + (i & 1) * 16];   \
    }
#define mt_dummy 0

    // ---------------- K loop: 9 taps x 8 chunks of 32 ch, barrier-free ------
    for (int tap = 0; tap < 9; ++tap) {
        const int dh = tap / 3 - 1, dw = tap % 3 - 1;
        const int rowpar = ((l32 >> 3) + 1 + dh) & 1;   // mt*4 is even
        int sbase[2], sx[2];
#pragma unroll
        for (int mt = 0; mt < 2; ++mt) {
            const int p = pLane32 + (mt * 4 + dh) * 10 + dw;
            sbase[mt] = p * 256;
            sx[mt]    = (p & 7) | (rowpar << 3);
        }
        CHUNK(0, wqE) CHUNK(1, wqO) CHUNK(2, wqE) CHUNK(3, wqO)
        CHUNK(4, wqE) CHUNK(5, wqO) CHUNK(6, wqE) CHUNK(7, wqO)
    }
#undef CHUNK
#undef mt_dummy

    __syncthreads();   // halo dead; reuse SMEM[0,16384) as Sh half

    // ---------------- epilogue: bias+relu -> Sh (64px x 256ch, swizzled) ----
    // 32x32 D-layout: n = wv*64 + nt*32 + l32 (local),
    //                 px = mt*32 + (r&3) + 8*(r>>2) + 4*hi
#pragma unroll
    for (int nt = 0; nt < 2; ++nt) {
        const int nl = wv * 64 + nt * 32 + l32;            // local channel
        const float bn = ldmix(bsh, nhalf * 256 + nl, isb16);
#pragma unroll
        for (int mt = 0; mt < 2; ++mt) {
#pragma unroll
            for (int r = 0; r < 16; ++r) {
                const int px = mt * 32 + (r & 3) + 8 * (r >> 2) + 4 * hi;
                float vv = acc[mt][nt][r] + bn;
                vv = vv > 0.f ? vv : 0.f;
                SMEM[px * 256 + (nl ^ ((px & 7) * 8))] = f2b(vv);
            }
        }
    }
    __syncthreads();

    // ---------------- partial GEMM2: W18[:, half] x Sh^T (16x16) ------------
    const f32x4 zf = {0.f, 0.f, 0.f, 0.f};
    f32x4 a2[2];
    a2[0] = zf; a2[1] = zf;
    const int px2 = wv * 16 + l16;
#pragma unroll
    for (int jt = 0; jt < 2; ++jt) {
#pragma unroll
        for (int ksl = 0; ksl < 8; ++ksl) {
            bf16x8 wa = *(const bf16x8*)
                &W18p[(jt * 16 + l16) * 512 + nhalf * 256 + ksl * 32 + quad * 8];
            bf16x8 sb = *(const bf16x8*)
                &SMEM[px2 * 256 + ((ksl * 32 + quad * 8) ^ ((px2 & 7) * 8))];
            a2[jt] = __builtin_amdgcn_mfma_f32_16x16x32_bf16(wa, sb, a2[jt], 0, 0, 0);
        }
    }

    // ---------------- store f32 partials ------------------------------------
    const int Pimg = (h0 + (px2 >> 3)) * S + (w0 + (px2 & 7));
    const int pixG = b * 87296 + lvlPixOff + Pimg;
    float* P = Ppart + (size_t)nhalf * PART_ELEMS + (size_t)pixG * 18;
    *(f32x4*)&P[quad * 4] = a2[0];                  // j = quad*4 + r (0..15)
    if (quad == 0) { P[16] = a2[1][0]; P[17] = a2[1][1]; }
}

// ---------------------------------------------------------------------------
// Finalize: sum halves, bias, softmax, store outputs. rowBase = 3*pixG.
// ---------------------------------------------------------------------------
__global__ __launch_bounds__(256) void rpn_finalize(
    const float* __restrict__ P0, const float* __restrict__ P1,
    const void* __restrict__ bcls, const void* __restrict__ bdelta,
    void* __restrict__ out, const int* __restrict__ flag)
{
    const bool isb16 = (*flag != 0);
    const int pixG = blockIdx.x * 256 + threadIdx.x;
    if (pixG >= NPIX) return;

    float v[18];
#pragma unroll
    for (int j = 0; j < 18; ++j)
        v[j] = P0[(size_t)pixG * 18 + j] + P1[(size_t)pixG * 18 + j];

    const size_t rowBase = (size_t)pixG * 3;
    u16*   o16 = (u16*)out;
    float* o32 = (float*)out;
    auto storeOut = [&](size_t idx, float val) {
        if (isb16) o16[idx] = f2b(val); else o32[idx] = val;
    };

    // deltas: j in [6,18)
#pragma unroll
    for (int dj = 0; dj < 12; ++dj) {
        float vv = v[6 + dj] + ldmix(bdelta, dj, isb16);
        storeOut(DELTAS_OFF + (rowBase + (dj >> 2)) * 4 + (dj & 3), vv);
    }
    // cls logits + softmax
#pragma unroll
    for (int r = 0; r < 3; ++r) {
        const float L0 = v[2 * r]     + ldmix(bcls, 2 * r, isb16);
        const float L1 = v[2 * r + 1] + ldmix(bcls, 2 * r + 1, isb16);
        const size_t row = rowBase + r;
        storeOut(LOGITS_OFF + row * 2 + 0, L0);
        storeOut(LOGITS_OFF + row * 2 + 1, L1);
        const float m = fmaxf(L0, L1);
        const float e0 = __expf(L0 - m), e1 = __expf(L1 - m);
        const float inv = 1.0f / (e0 + e1);
        storeOut(PROBS_OFF + row * 2 + 0, e0 * inv);
        storeOut(PROBS_OFF + row * 2 + 1, e1 * inv);
    }
}

// ---------------------------------------------------------------------------
// Fallback fused kernel (harness-verified at 601 us) if workspace too small.
// ---------------------------------------------------------------------------
__global__ __launch_bounds__(256, 2) void rpn_fused(
    const void* __restrict__ f0, const void* __restrict__ f1,
    const void* __restrict__ f2, const void* __restrict__ f3,
    const void* __restrict__ f4,
    const void* __restrict__ bsh, const void* __restrict__ bcls,
    const void* __restrict__ bdelta,
    const u16* __restrict__ W3p, const u16* __restrict__ W18p,
    void* __restrict__ out, const int* __restrict__ flag)
{
    __shared__ u16 SMEM[32768];

    const bool isb16 = (*flag != 0);

    const int tid  = threadIdx.x;
    const int wv   = tid >> 6;
    const int lane = tid & 63;
    const int quad = lane >> 4;
    const int l16  = lane & 15;

    const int bid = blockIdx.x;
    const int lvl = (bid >= 2048) + (bid >= 2560) + (bid >= 2688) + (bid >= 2720);
    const int tileBase = (lvl == 0) ? 0 : (lvl == 1) ? 2048 : (lvl == 2) ? 2560
                        : (lvl == 3) ? 2688 : 2720;
    const int logS   = 8 - lvl;
    const int S      = 1 << logS;
    const int rowOff = (lvl == 0) ? 0 : (lvl == 1) ? 196608 : (lvl == 2) ? 245760
                      : (lvl == 3) ? 258048 : 261120;
    const void* feat = (lvl == 0) ? f0 : (lvl == 1) ? f1 : (lvl == 2) ? f2
                      : (lvl == 3) ? f3 : f4;
    const int tile = bid - tileBase;

    const int logT = logS - 3;
    const int b    = tile >> (2 * logT);
    const int t2   = tile & ((1 << (2 * logT)) - 1);
    const int th   = t2 >> logT;
    const int tw   = t2 & ((1 << logT) - 1);
    const int h0   = th << 3, w0 = tw << 3;

    for (int g = tid; g < 3200; g += 256) {
        const int p  = g >> 5;
        const int cg = g & 31;
        const int hh = p / 10;
        const int ww = p - hh * 10;
        const int ih = h0 + hh - 1;
        const int iw = w0 + ww - 1;
        uint4 v; v.x = 0u; v.y = 0u; v.z = 0u; v.w = 0u;
        if (ih >= 0 && ih < S && iw >= 0 && iw < S) {
            const size_t gaddr = ((size_t)((b * S + ih) * S + iw)) * 256 + cg * 8;
            if (isb16) {
                v = *(const uint4*)((const u16*)feat + gaddr);
            } else {
                const float* fp = (const float*)feat + gaddr;
                float4 x = *(const float4*)fp;
                float4 y = *(const float4*)(fp + 4);
                v.x = (u32)f2b(x.x) | ((u32)f2b(x.y) << 16);
                v.y = (u32)f2b(x.z) | ((u32)f2b(x.w) << 16);
                v.z = (u32)f2b(y.x) | ((u32)f2b(y.y) << 16);
                v.w = (u32)f2b(y.z) | ((u32)f2b(y.w) << 16);
            }
        }
        *(uint4*)&SMEM[p * 256 + ((cg ^ (p & 7)) << 3)] = v;
    }
    __syncthreads();

    const f32x4 zf = {0.f, 0.f, 0.f, 0.f};
    f32x4 acc[4][8];
#pragma unroll
    for (int mt = 0; mt < 4; ++mt)
#pragma unroll
        for (int nt = 0; nt < 8; ++nt) acc[mt][nt] = zf;

    const int pLane0 = ((l16 >> 3) + 1) * 10 + (l16 & 7) + 1;
    const int wbase  = (wv * 128 + l16) * 32 + quad * 8;

    for (int tap = 0; tap < 9; ++tap) {
        const int dh = tap / 3 - 1, dw = tap % 3 - 1;
        int sbase[4], sx[4];
#pragma unroll
        for (int mt = 0; mt < 4; ++mt) {
            const int p = pLane0 + (mt * 2 + dh) * 10 + dw;
            sbase[mt] = p * 256;
            sx[mt]    = p & 7;
        }
        const u16* Wk = &W3p[tap * 8 * 16384 + wbase];
#pragma unroll
        for (int cc = 0; cc < 8; ++cc) {
            bf16x8 bfr[8];
#pragma unroll
            for (int nt = 0; nt < 8; ++nt)
                bfr[nt] = *(const bf16x8*)&Wk[cc * 16384 + nt * 512];
#pragma unroll
            for (int mt = 0; mt < 4; ++mt) {
                const bf16x8 af = *(const bf16x8*)
                    &SMEM[sbase[mt] + (((cc * 4 + quad) ^ sx[mt]) << 3)];
#pragma unroll
                for (int nt = 0; nt < 8; ++nt)
                    acc[mt][nt] = __builtin_amdgcn_mfma_f32_16x16x32_bf16(
                        af, bfr[nt], acc[mt][nt], 0, 0, 0);
            }
        }
    }

    __syncthreads();

#pragma unroll
    for (int nt = 0; nt < 8; ++nt) {
        const int n = wv * 128 + nt * 16 + l16;
        const float bn = ldmix(bsh, n, isb16);
#pragma unroll
        for (int mt = 0; mt < 4; ++mt) {
#pragma unroll
            for (int r = 0; r < 4; ++r) {
                const int px = mt * 16 + quad * 4 + r;
                float vv = acc[mt][nt][r] + bn;
                vv = vv > 0.f ? vv : 0.f;
                SMEM[sh_idx(px, n)] = f2b(vv);
            }
        }
    }
    __syncthreads();

    f32x4 a2[2];
    a2[0] = zf; a2[1] = zf;
#pragma unroll
    for (int jt = 0; jt < 2; ++jt) {
#pragma unroll
        for (int ks = 0; ks < 16; ++ks) {
            bf16x8 wa = *(const bf16x8*)&W18p[(jt * 16 + l16) * 512 + ks * 32 + quad * 8];
            bf16x8 sb = *(const bf16x8*)&SMEM[sh_idx(wv * 16 + l16, ks * 32 + quad * 8)];
            a2[jt] = __builtin_amdgcn_mfma_f32_16x16x32_bf16(wa, sb, a2[jt], 0, 0, 0);
        }
    }

    const int px2  = wv * 16 + l16;
    const int Pimg = (h0 + (px2 >> 3)) * S + (w0 + (px2 & 7));
    const size_t rowBase = (size_t)b * TR + rowOff + (size_t)Pimg * 3;
    u16*   o16 = (u16*)out;
    float* o32 = (float*)out;
    auto storeOut = [&](size_t idx, float v) {
        if (isb16) o16[idx] = f2b(v); else o32[idx] = v;
    };

#pragma unroll
    for (int jt = 0; jt < 2; ++jt) {
#pragma unroll
        for (int r = 0; r < 4; ++r) {
            const int j = jt * 16 + quad * 4 + r;
            if (j >= 6 && j < 18) {
                const int dj = j - 6;
                float vv = a2[jt][r] + ldmix(bdelta, dj, isb16);
                storeOut(DELTAS_OFF + (rowBase + (dj >> 2)) * 4 + (dj & 3), vv);
            }
        }
    }
    auto writePair = [&](int r, float v0, float v1) {
        const float bl0 = ldmix(bcls, 2 * r, isb16);
        const float bl1 = ldmix(bcls, 2 * r + 1, isb16);
        const float L0 = v0 + bl0, L1 = v1 + bl1;
        const size_t row = rowBase + r;
        storeOut(LOGITS_OFF + row * 2 + 0, L0);
        storeOut(LOGITS_OFF + row * 2 + 1, L1);
        const float m = fmaxf(L0, L1);
        const float e0 = __expf(L0 - m), e1 = __expf(L1 - m);
        const float inv = 1.0f / (e0 + e1);
        storeOut(PROBS_OFF + row * 2 + 0, e0 * inv);
        storeOut(PROBS_OFF + row * 2 + 1, e1 * inv);
    };
    if (quad == 0) {
        writePair(0, a2[0][0], a2[0][1]);
        writePair(1, a2[0][2], a2[0][3]);
    } else if (quad == 1) {
        writePair(2, a2[0][0], a2[0][1]);
    }
}

// ---------------------------------------------------------------------------
extern "C" void kernel_launch(void* const* d_in, const int* in_sizes, int n_in,
                              void* d_out, int out_size, void* d_ws, size_t ws_size,
                              hipStream_t stream) {
    const void* f0     = d_in[0];
    const void* f1     = d_in[1];
    const void* f2     = d_in[2];
    const void* f3     = d_in[3];
    const void* f4     = d_in[4];
    const void* w3     = d_in[5];
    const void* bsh    = d_in[6];
    const void* wcls   = d_in[7];
    const void* bcls   = d_in[8];
    const void* wdelta = d_in[9];
    const void* bdelta = d_in[10];

    u16* W3p  = (u16*)d_ws;
    u16* W18p = W3p + W3P_ELEMS;
    int* flag = (int*)((char*)d_ws + FLAG_OFF_BYTES);

    detect_kernel<<<1, 64, 0, stream>>>((const u16*)f0, flag);
    repack_kernel<<<4672, 256, 0, stream>>>(w3, wcls, wdelta, W3p, W18p, flag);

    const size_t NEED = (size_t)PART0_OFF + 2ull * PART_BYTES;   // ~27.5 MB
    if (ws_size >= NEED) {
        float* P0 = (float*)((char*)d_ws + PART0_OFF);
        float* P1 = P0 + PART_ELEMS;
        rpn_conv<<<5456, 256, 0, stream>>>(f0, f1, f2, f3, f4, bsh,
                                           W3p, W18p, P0, flag);
        rpn_finalize<<<682, 256, 0, stream>>>(P0, P1, bcls, bdelta, d_out, flag);
    } else {
        rpn_fused<<<2728, 256, 0, stream>>>(f0, f1, f2, f3, f4,
                                            bsh, bcls, bdelta, W3p, W18p,
                                            d_out, flag);
    }
}

// Round 11
// 647.659 us; speedup vs baseline: 1.0646x; 1.0646x over previous
//
#include <hip/hip_runtime.h>

typedef unsigned short u16;
typedef unsigned int u32;
typedef __attribute__((ext_vector_type(8))) short bf16x8;
typedef __attribute__((ext_vector_type(4))) float f32x4;
typedef __attribute__((ext_vector_type(16))) float f32x16;

#define TR 261888           // total anchor rows per batch image
#define LOGITS_OFF 0
#define PROBS_OFF  1047552  // 2*TR*2
#define DELTAS_OFF 2095104  // 2*(2*TR*2)

#define W3P_ELEMS (72 * 512 * 32)
#define W18P_ELEMS (32 * 512)
#define FLAG_OFF_BYTES ((W3P_ELEMS + W18P_ELEMS) * 2)   // 2,392,064
#define PART0_OFF 2392320                                // 256-aligned
#define NPIX 174592                                      // total pixels (2 batches)
#define PART_ELEMS (NPIX * 18)
#define PART_BYTES (PART_ELEMS * 4)

__device__ __forceinline__ float b2f(u16 u) {
    union { u32 i; float f; } v; v.i = ((u32)u) << 16; return v.f;
}
__device__ __forceinline__ u16 f2b(float f) {
    union { float f; u32 i; } v; v.f = f;
    u32 x = v.i;
    return (u16)((x + 0x7fffu + ((x >> 16) & 1u)) >> 16);
}
__device__ __forceinline__ float ldmix(const void* p, int i, bool isb16) {
    return isb16 ? b2f(((const u16*)p)[i]) : ((const float*)p)[i];
}

// Sh layout (fused fallback): 64 px x 512 ch, stride 512, XOR swizzle.
__device__ __forceinline__ int sh_idx(int px, int c) {
    return px * 512 + (c ^ ((px & 3) * 8));
}

// ---------------------------------------------------------------------------
// Detect input dtype.
// ---------------------------------------------------------------------------
__global__ void detect_kernel(const u16* __restrict__ f0, int* __restrict__ flag) {
    int lane = threadIdx.x;          // 64 threads
    u16 v = f0[lane * 2];            // even u16 index
    int e = (v >> 7) & 0xFF;
    bool plausible = (e >= 90) && (e <= 140);
    unsigned long long m = __ballot(plausible);
    if (lane == 0) *flag = (__popcll(m) >= 48) ? 1 : 0;   // 1 = bf16, 0 = f32
}

// ---------------------------------------------------------------------------
// Repack: w_shared [2304,512] -> W3p[72][512][32] bf16
//   w_cls[512,6] + w_delta[512,12] -> W18p[32][512] bf16 (rows 18..31 = 0)
// ---------------------------------------------------------------------------
__global__ void repack_kernel(const void* __restrict__ w3,
                              const void* __restrict__ wcls,
                              const void* __restrict__ wdelta,
                              u16* __restrict__ W3p, u16* __restrict__ W18p,
                              const int* __restrict__ flag) {
    const bool isb16 = (*flag != 0);
    int tid = blockIdx.x * 256 + threadIdx.x;
    if (tid < W3P_ELEMS) {
        int k = tid & 31;
        int n = (tid >> 5) & 511;
        int c = tid >> 14;
        int K = c * 32 + k;          // global k index 0..2303
        float v = ldmix(w3, K * 512 + n, isb16);
        W3p[tid] = f2b(v);
    } else if (tid < W3P_ELEMS + W18P_ELEMS) {
        int t = tid - W3P_ELEMS;
        int k = t & 511;
        int j = t >> 9;
        float v = 0.f;
        if (j < 6)       v = ldmix(wcls, k * 6 + j, isb16);
        else if (j < 18) v = ldmix(wdelta, k * 12 + (j - 6), isb16);
        W18p[t] = f2b(v);
    }
}

// ---------------------------------------------------------------------------
// N-split conv kernel, 32x32x16 MFMA (R10 structure, measured 527 us) with a
// DEPTH-4 W prefetch queue: refill wq[cc&3] <- chunk kc+4 right after its
// consuming MFMAs -> issue-to-use slack ~3 chunks (~2400 cy) >> loaded-L2
// latency. Targets the measured near-serial pipe behavior (sum-of-floors).
// One block = one 8x8 tile x one 256-channel half; 3 waves/SIMD.
// Halo swizzle: slot = cg ^ ((p&7) | ((row&1)<<3)) -> 32-lane A-read 2-way.
// ---------------------------------------------------------------------------
__global__ __launch_bounds__(256, 3) void rpn_conv(
    const void* __restrict__ f0, const void* __restrict__ f1,
    const void* __restrict__ f2, const void* __restrict__ f3,
    const void* __restrict__ f4,
    const void* __restrict__ bsh,
    const u16* __restrict__ W3p, const u16* __restrict__ W18p,
    float* __restrict__ Ppart, const int* __restrict__ flag)
{
    __shared__ u16 SMEM[25600];   // 51,200 B: halo 100px x 256ch bf16

    const bool isb16 = (*flag != 0);

    const int tid  = threadIdx.x;
    const int wv   = tid >> 6;
    const int lane = tid & 63;
    const int l32  = lane & 31;
    const int hi   = lane >> 5;          // 0/1: k-half selector for 32x32x16
    const int quad = lane >> 4;          // for GEMM2 (16x16)
    const int l16  = lane & 15;

    const int gid    = blockIdx.x;
    const int tileId = gid >> 1;
    const int nhalf  = gid & 1;

    const int lvl = (tileId >= 2048) + (tileId >= 2560) + (tileId >= 2688) + (tileId >= 2720);
    const int tileBase = (lvl == 0) ? 0 : (lvl == 1) ? 2048 : (lvl == 2) ? 2560
                        : (lvl == 3) ? 2688 : 2720;
    const int logS   = 8 - lvl;
    const int S      = 1 << logS;
    const int lvlPixOff = (lvl == 0) ? 0 : (lvl == 1) ? 65536 : (lvl == 2) ? 81920
                         : (lvl == 3) ? 86016 : 87040;
    const void* feat = (lvl == 0) ? f0 : (lvl == 1) ? f1 : (lvl == 2) ? f2
                      : (lvl == 3) ? f3 : f4;
    const int tile = tileId - tileBase;

    const int logT = logS - 3;
    const int b    = tile >> (2 * logT);
    const int t2   = tile & ((1 << (2 * logT)) - 1);
    const int th   = t2 >> logT;
    const int tw   = t2 & ((1 << logT) - 1);
    const int h0   = th << 3, w0 = tw << 3;

    // ---------------- stage 10x10x256 halo -> LDS (bf16, 4-bit swizzle) -----
    for (int g = tid; g < 3200; g += 256) {
        const int p  = g >> 5;
        const int cg = g & 31;
        const int hh = p / 10;
        const int ww = p - hh * 10;
        const int ih = h0 + hh - 1;
        const int iw = w0 + ww - 1;
        uint4 v; v.x = 0u; v.y = 0u; v.z = 0u; v.w = 0u;
        if (ih >= 0 && ih < S && iw >= 0 && iw < S) {
            const size_t gaddr = ((size_t)((b * S + ih) * S + iw)) * 256 + cg * 8;
            if (isb16) {
                v = *(const uint4*)((const u16*)feat + gaddr);
            } else {
                const float* fp = (const float*)feat + gaddr;
                float4 x = *(const float4*)fp;
                float4 y = *(const float4*)(fp + 4);
                v.x = (u32)f2b(x.x) | ((u32)f2b(x.y) << 16);
                v.y = (u32)f2b(x.z) | ((u32)f2b(x.w) << 16);
                v.z = (u32)f2b(y.x) | ((u32)f2b(y.y) << 16);
                v.w = (u32)f2b(y.z) | ((u32)f2b(y.w) << 16);
            }
        }
        const int sw = (p & 7) | ((hh & 1) << 3);
        *(uint4*)&SMEM[p * 256 + ((cg ^ sw) << 3)] = v;
    }
    __syncthreads();

    f32x16 acc[2][2];
#pragma unroll
    for (int mt = 0; mt < 2; ++mt)
#pragma unroll
        for (int nt = 0; nt < 2; ++nt)
#pragma unroll
            for (int r = 0; r < 16; ++r) acc[mt][nt][r] = 0.f;

    // lane's base halo pixel for Mt=0, center tap: px = l32 -> (row,col)
    const int pLane32 = ((l32 >> 3) + 1) * 10 + (l32 & 7) + 1;
    // W base: n = nhalf*256 + wv*64 + Nt*32 + l32, k-offset hi*8 within chunk
    const u16* __restrict__ Wp =
        W3p + (u32)(nhalf * 256 + wv * 64 + l32) * 32 + (u32)hi * 8;

    // depth-4 W queue: frag index = Nt*2 + ks -> Wp[kc*16384 + Nt*1024 + ks*16]
    bf16x8 wq0[4], wq1[4], wq2[4], wq3[4];
#pragma unroll
    for (int i = 0; i < 4; ++i) {
        wq0[i] = *(const bf16x8*)&Wp[0 * 16384 + (i >> 1) * 1024 + (i & 1) * 16];
        wq1[i] = *(const bf16x8*)&Wp[1 * 16384 + (i >> 1) * 1024 + (i & 1) * 16];
        wq2[i] = *(const bf16x8*)&Wp[2 * 16384 + (i >> 1) * 1024 + (i & 1) * 16];
        wq3[i] = *(const bf16x8*)&Wp[3 * 16384 + (i >> 1) * 1024 + (i & 1) * 16];
    }

    // one chunk: 4 ds_read A-frags (Mt x ks), 8 MFMA 32x32x16, refill <- kc+4
#define CHUNK(CC, WQ)                                                         \
    {                                                                         \
        const int kc = tap * 8 + (CC);                                        \
        bf16x8 af[2][2];                                                      \
        _Pragma("unroll")                                                     \
        for (int mt = 0; mt < 2; ++mt)                                        \
            _Pragma("unroll")                                                 \
            for (int ks = 0; ks < 2; ++ks)                                    \
                af[mt][ks] = *(const bf16x8*)                                 \
                    &SMEM[sbase[mt] +                                         \
                          ((((CC) * 4 + ks * 2 + hi) ^ sx[mt]) << 3)];        \
        __builtin_amdgcn_s_setprio(1);                                        \
        _Pragma("unroll")                                                     \
        for (int ks = 0; ks < 2; ++ks)                                        \
            _Pragma("unroll")                                                 \
            for (int nt = 0; nt < 2; ++nt) {                                  \
                acc[0][nt] = __builtin_amdgcn_mfma_f32_32x32x16_bf16(         \
                    af[0][ks], WQ[nt * 2 + ks], acc[0][nt], 0, 0, 0);         \
                acc[1][nt] = __builtin_amdgcn_mfma_f32_32x32x16_bf16(         \
                    af[1][ks], WQ[nt * 2 + ks], acc[1][nt], 0, 0, 0);         \
            }                                                                 \
        __builtin_amdgcn_s_setprio(0);                                        \
        const int kpre = (kc + 4 < 72) ? (kc + 4) : kc;                       \
        _Pragma("unroll")                                                     \
        for (int i = 0; i < 4; ++i)                                           \
            WQ[i] = *(const bf16x8*)                                          \
                &Wp[(size_t)kpre * 16384 + (i >> 1) * 1024 + (i & 1) * 16];   \
    }

    // ---------------- K loop: 9 taps x 8 chunks of 32 ch, barrier-free ------
    for (int tap = 0; tap < 9; ++tap) {
        const int dh = tap / 3 - 1, dw = tap % 3 - 1;
        const int rowpar = ((l32 >> 3) + 1 + dh) & 1;   // mt*4 is even
        int sbase[2], sx[2];
#pragma unroll
        for (int mt = 0; mt < 2; ++mt) {
            const int p = pLane32 + (mt * 4 + dh) * 10 + dw;
            sbase[mt] = p * 256;
            sx[mt]    = (p & 7) | (rowpar << 3);
        }
        CHUNK(0, wq0) CHUNK(1, wq1) CHUNK(2, wq2) CHUNK(3, wq3)
        CHUNK(4, wq0) CHUNK(5, wq1) CHUNK(6, wq2) CHUNK(7, wq3)
    }
#undef CHUNK

    __syncthreads();   // halo dead; reuse SMEM[0,16384) as Sh half

    // ---------------- epilogue: bias+relu -> Sh (64px x 256ch, swizzled) ----
    // 32x32 D-layout: n = wv*64 + nt*32 + l32 (local),
    //                 px = mt*32 + (r&3) + 8*(r>>2) + 4*hi
#pragma unroll
    for (int nt = 0; nt < 2; ++nt) {
        const int nl = wv * 64 + nt * 32 + l32;            // local channel
        const float bn = ldmix(bsh, nhalf * 256 + nl, isb16);
#pragma unroll
        for (int mt = 0; mt < 2; ++mt) {
#pragma unroll
            for (int r = 0; r < 16; ++r) {
                const int px = mt * 32 + (r & 3) + 8 * (r >> 2) + 4 * hi;
                float vv = acc[mt][nt][r] + bn;
                vv = vv > 0.f ? vv : 0.f;
                SMEM[px * 256 + (nl ^ ((px & 7) * 8))] = f2b(vv);
            }
        }
    }
    __syncthreads();

    // ---------------- partial GEMM2: W18[:, half] x Sh^T (16x16) ------------
    const f32x4 zf = {0.f, 0.f, 0.f, 0.f};
    f32x4 a2[2];
    a2[0] = zf; a2[1] = zf;
    const int px2 = wv * 16 + l16;
#pragma unroll
    for (int jt = 0; jt < 2; ++jt) {
#pragma unroll
        for (int ksl = 0; ksl < 8; ++ksl) {
            bf16x8 wa = *(const bf16x8*)
                &W18p[(jt * 16 + l16) * 512 + nhalf * 256 + ksl * 32 + quad * 8];
            bf16x8 sb = *(const bf16x8*)
                &SMEM[px2 * 256 + ((ksl * 32 + quad * 8) ^ ((px2 & 7) * 8))];
            a2[jt] = __builtin_amdgcn_mfma_f32_16x16x32_bf16(wa, sb, a2[jt], 0, 0, 0);
        }
    }

    // ---------------- store f32 partials ------------------------------------
    const int Pimg = (h0 + (px2 >> 3)) * S + (w0 + (px2 & 7));
    const int pixG = b * 87296 + lvlPixOff + Pimg;
    float* P = Ppart + (size_t)nhalf * PART_ELEMS + (size_t)pixG * 18;
    *(f32x4*)&P[quad * 4] = a2[0];                  // j = quad*4 + r (0..15)
    if (quad == 0) { P[16] = a2[1][0]; P[17] = a2[1][1]; }
}

// ---------------------------------------------------------------------------
// Finalize: sum halves, bias, softmax, store outputs. rowBase = 3*pixG.
// ---------------------------------------------------------------------------
__global__ __launch_bounds__(256) void rpn_finalize(
    const float* __restrict__ P0, const float* __restrict__ P1,
    const void* __restrict__ bcls, const void* __restrict__ bdelta,
    void* __restrict__ out, const int* __restrict__ flag)
{
    const bool isb16 = (*flag != 0);
    const int pixG = blockIdx.x * 256 + threadIdx.x;
    if (pixG >= NPIX) return;

    float v[18];
#pragma unroll
    for (int j = 0; j < 18; ++j)
        v[j] = P0[(size_t)pixG * 18 + j] + P1[(size_t)pixG * 18 + j];

    const size_t rowBase = (size_t)pixG * 3;
    u16*   o16 = (u16*)out;
    float* o32 = (float*)out;
    auto storeOut = [&](size_t idx, float val) {
        if (isb16) o16[idx] = f2b(val); else o32[idx] = val;
    };

    // deltas: j in [6,18)
#pragma unroll
    for (int dj = 0; dj < 12; ++dj) {
        float vv = v[6 + dj] + ldmix(bdelta, dj, isb16);
        storeOut(DELTAS_OFF + (rowBase + (dj >> 2)) * 4 + (dj & 3), vv);
    }
    // cls logits + softmax
#pragma unroll
    for (int r = 0; r < 3; ++r) {
        const float L0 = v[2 * r]     + ldmix(bcls, 2 * r, isb16);
        const float L1 = v[2 * r + 1] + ldmix(bcls, 2 * r + 1, isb16);
        const size_t row = rowBase + r;
        storeOut(LOGITS_OFF + row * 2 + 0, L0);
        storeOut(LOGITS_OFF + row * 2 + 1, L1);
        const float m = fmaxf(L0, L1);
        const float e0 = __expf(L0 - m), e1 = __expf(L1 - m);
        const float inv = 1.0f / (e0 + e1);
        storeOut(PROBS_OFF + row * 2 + 0, e0 * inv);
        storeOut(PROBS_OFF + row * 2 + 1, e1 * inv);
    }
}

// ---------------------------------------------------------------------------
// Fallback fused kernel (harness-verified at 601 us) if workspace too small.
// ---------------------------------------------------------------------------
__global__ __launch_bounds__(256, 2) void rpn_fused(
    const void* __restrict__ f0, const void* __restrict__ f1,
    const void* __restrict__ f2, const void* __restrict__ f3,
    const void* __restrict__ f4,
    const void* __restrict__ bsh, const void* __restrict__ bcls,
    const void* __restrict__ bdelta,
    const u16* __restrict__ W3p, const u16* __restrict__ W18p,
    void* __restrict__ out, const int* __restrict__ flag)
{
    __shared__ u16 SMEM[32768];

    const bool isb16 = (*flag != 0);

    const int tid  = threadIdx.x;
    const int wv   = tid >> 6;
    const int lane = tid & 63;
    const int quad = lane >> 4;
    const int l16  = lane & 15;

    const int bid = blockIdx.x;
    const int lvl = (bid >= 2048) + (bid >= 2560) + (bid >= 2688) + (bid >= 2720);
    const int tileBase = (lvl == 0) ? 0 : (lvl == 1) ? 2048 : (lvl == 2) ? 2560
                        : (lvl == 3) ? 2688 : 2720;
    const int logS   = 8 - lvl;
    const int S      = 1 << logS;
    const int rowOff = (lvl == 0) ? 0 : (lvl == 1) ? 196608 : (lvl == 2) ? 245760
                      : (lvl == 3) ? 258048 : 261120;
    const void* feat = (lvl == 0) ? f0 : (lvl == 1) ? f1 : (lvl == 2) ? f2
                      : (lvl == 3) ? f3 : f4;
    const int tile = bid - tileBase;

    const int logT = logS - 3;
    const int b    = tile >> (2 * logT);
    const int t2   = tile & ((1 << (2 * logT)) - 1);
    const int th   = t2 >> logT;
    const int tw   = t2 & ((1 << logT) - 1);
    const int h0   = th << 3, w0 = tw << 3;

    for (int g = tid; g < 3200; g += 256) {
        const int p  = g >> 5;
        const int cg = g & 31;
        const int hh = p / 10;
        const int ww = p - hh * 10;
        const int ih = h0 + hh - 1;
        const int iw = w0 + ww - 1;
        uint4 v; v.x = 0u; v.y = 0u; v.z = 0u; v.w = 0u;
        if (ih >= 0 && ih < S && iw >= 0 && iw < S) {
            const size_t gaddr = ((size_t)((b * S + ih) * S + iw)) * 256 + cg * 8;
            if (isb16) {
                v = *(const uint4*)((const u16*)feat + gaddr);
            } else {
                const float* fp = (const float*)feat + gaddr;
                float4 x = *(const float4*)fp;
                float4 y = *(const float4*)(fp + 4);
                v.x = (u32)f2b(x.x) | ((u32)f2b(x.y) << 16);
                v.y = (u32)f2b(x.z) | ((u32)f2b(x.w) << 16);
                v.z = (u32)f2b(y.x) | ((u32)f2b(y.y) << 16);
                v.w = (u32)f2b(y.z) | ((u32)f2b(y.w) << 16);
            }
        }
        *(uint4*)&SMEM[p * 256 + ((cg ^ (p & 7)) << 3)] = v;
    }
    __syncthreads();

    const f32x4 zf = {0.f, 0.f, 0.f, 0.f};
    f32x4 acc[4][8];
#pragma unroll
    for (int mt = 0; mt < 4; ++mt)
#pragma unroll
        for (int nt = 0; nt < 8; ++nt) acc[mt][nt] = zf;

    const int pLane0 = ((l16 >> 3) + 1) * 10 + (l16 & 7) + 1;
    const int wbase  = (wv * 128 + l16) * 32 + quad * 8;

    for (int tap = 0; tap < 9; ++tap) {
        const int dh = tap / 3 - 1, dw = tap % 3 - 1;
        int sbase[4], sx[4];
#pragma unroll
        for (int mt = 0; mt < 4; ++mt) {
            const int p = pLane0 + (mt * 2 + dh) * 10 + dw;
            sbase[mt] = p * 256;
            sx[mt]    = p & 7;
        }
        const u16* Wk = &W3p[tap * 8 * 16384 + wbase];
#pragma unroll
        for (int cc = 0; cc < 8; ++cc) {
            bf16x8 bfr[8];
#pragma unroll
            for (int nt = 0; nt < 8; ++nt)
                bfr[nt] = *(const bf16x8*)&Wk[cc * 16384 + nt * 512];
#pragma unroll
            for (int mt = 0; mt < 4; ++mt) {
                const bf16x8 af = *(const bf16x8*)
                    &SMEM[sbase[mt] + (((cc * 4 + quad) ^ sx[mt]) << 3)];
#pragma unroll
                for (int nt = 0; nt < 8; ++nt)
                    acc[mt][nt] = __builtin_amdgcn_mfma_f32_16x16x32_bf16(
                        af, bfr[nt], acc[mt][nt], 0, 0, 0);
            }
        }
    }

    __syncthreads();

#pragma unroll
    for (int nt = 0; nt < 8; ++nt) {
        const int n = wv * 128 + nt * 16 + l16;
        const float bn = ldmix(bsh, n, isb16);
#pragma unroll
        for (int mt = 0; mt < 4; ++mt) {
#pragma unroll
            for (int r = 0; r < 4; ++r) {
                const int px = mt * 16 + quad * 4 + r;
                float vv = acc[mt][nt][r] + bn;
                vv = vv > 0.f ? vv : 0.f;
                SMEM[sh_idx(px, n)] = f2b(vv);
            }
        }
    }
    __syncthreads();

    f32x4 a2[2];
    a2[0] = zf; a2[1] = zf;
#pragma unroll
    for (int jt = 0; jt < 2; ++jt) {
#pragma unroll
        for (int ks = 0; ks < 16; ++ks) {
            bf16x8 wa = *(const bf16x8*)&W18p[(jt * 16 + l16) * 512 + ks * 32 + quad * 8];
            bf16x8 sb = *(const bf16x8*)&SMEM[sh_idx(wv * 16 + l16, ks * 32 + quad * 8)];
            a2[jt] = __builtin_amdgcn_mfma_f32_16x16x32_bf16(wa, sb, a2[jt], 0, 0, 0);
        }
    }

    const int px2  = wv * 16 + l16;
    const int Pimg = (h0 + (px2 >> 3)) * S + (w0 + (px2 & 7));
    const size_t rowBase = (size_t)b * TR + rowOff + (size_t)Pimg * 3;
    u16*   o16 = (u16*)out;
    float* o32 = (float*)out;
    auto storeOut = [&](size_t idx, float v) {
        if (isb16) o16[idx] = f2b(v); else o32[idx] = v;
    };

#pragma unroll
    for (int jt = 0; jt < 2; ++jt) {
#pragma unroll
        for (int r = 0; r < 4; ++r) {
            const int j = jt * 16 + quad * 4 + r;
            if (j >= 6 && j < 18) {
                const int dj = j - 6;
                float vv = a2[jt][r] + ldmix(bdelta, dj, isb16);
                storeOut(DELTAS_OFF + (rowBase + (dj >> 2)) * 4 + (dj & 3), vv);
            }
        }
    }
    auto writePair = [&](int r, float v0, float v1) {
        const float bl0 = ldmix(bcls, 2 * r, isb16);
        const float bl1 = ldmix(bcls, 2 * r + 1, isb16);
        const float L0 = v0 + bl0, L1 = v1 + bl1;
        const size_t row = rowBase + r;
        storeOut(LOGITS_OFF + row * 2 + 0, L0);
        storeOut(LOGITS_OFF + row * 2 + 1, L1);
        const float m = fmaxf(L0, L1);
        const float e0 = __expf(L0 - m), e1 = __expf(L1 - m);
        const float inv = 1.0f / (e0 + e1);
        storeOut(PROBS_OFF + row * 2 + 0, e0 * inv);
        storeOut(PROBS_OFF + row * 2 + 1, e1 * inv);
    };
    if (quad == 0) {
        writePair(0, a2[0][0], a2[0][1]);
        writePair(1, a2[0][2], a2[0][3]);
    } else if (quad == 1) {
        writePair(2, a2[0][0], a2[0][1]);
    }
}

// ---------------------------------------------------------------------------
extern "C" void kernel_launch(void* const* d_in, const int* in_sizes, int n_in,
                              void* d_out, int out_size, void* d_ws, size_t ws_size,
                              hipStream_t stream) {
    const void* f0     = d_in[0];
    const void* f1     = d_in[1];
    const void* f2     = d_in[2];
    const void* f3     = d_in[3];
    const void* f4     = d_in[4];
    const void* w3     = d_in[5];
    const void* bsh    = d_in[6];
    const void* wcls   = d_in[7];
    const void* bcls   = d_in[8];
    const void* wdelta = d_in[9];
    const void* bdelta = d_in[10];

    u16* W3p  = (u16*)d_ws;
    u16* W18p = W3p + W3P_ELEMS;
    int* flag = (int*)((char*)d_ws + FLAG_OFF_BYTES);

    detect_kernel<<<1, 64, 0, stream>>>((const u16*)f0, flag);
    repack_kernel<<<4672, 256, 0, stream>>>(w3, wcls, wdelta, W3p, W18p, flag);

    const size_t NEED = (size_t)PART0_OFF + 2ull * PART_BYTES;   // ~27.5 MB
    if (ws_size >= NEED) {
        float* P0 = (float*)((char*)d_ws + PART0_OFF);
        float* P1 = P0 + PART_ELEMS;
        rpn_conv<<<5456, 256, 0, stream>>>(f0, f1, f2, f3, f4, bsh,
                                           W3p, W18p, P0, flag);
        rpn_finalize<<<682, 256, 0, stream>>>(P0, P1, bcls, bdelta, d_out, flag);
    } else {
        rpn_fused<<<2728, 256, 0, stream>>>(f0, f1, f2, f3, f4,
                                            bsh, bcls, bdelta, W3p, W18p,
                                            d_out, flag);
    }
}